// Round 17
// baseline (114.274 us; speedup 1.0000x reference)
//
#include <hip/hip_runtime.h>

#define N_NODES    50000
#define N_EDGES    625000
#define HIDDEN     128
#define NUM_GRAPHS 128
#define EPS_GN     1e-5f
#define FIXSCALE   1048576.0f   // 2^20 fixed point for degree accumulation
#define NGEMM_BLK  782          // (N_NODES + 63) / 64
#define NHIST_BLK  306          // ceil(N_EDGES/8/256)
#define NB_SCAN    196          // ceil(N_NODES/256)

typedef __bf16 bf16x8 __attribute__((ext_vector_type(8)));
typedef float  f32x4  __attribute__((ext_vector_type(4)));
typedef unsigned short u16x8 __attribute__((ext_vector_type(8)));
typedef unsigned long long u64;

__device__ inline unsigned short f2b(float f) {
    __bf16 b = (__bf16)f;
    return __builtin_bit_cast(unsigned short, b);
}
__device__ inline float b2f(unsigned short u) {
    unsigned int x = ((unsigned int)u) << 16;
    return __builtin_bit_cast(float, x);
}

// ---- workspace layout (4B units) ----
#define HB_OFF     0          // ushort[6,400,000] bf16(h)   -> 3,200,000 units
#define CNT64_OFF  3200000    // u64[50,000]                 -> 100,000 units
#define DINV_OFF   3300000    // float[50,000]
#define WB_OFF     3352000    // ushort[16,384]
#define GSTART_OFF 3362000    // int[129]
#define ROWS_OFF   3363000    // int[50,001]
#define BSUM_OFF   3414000    // int[256]
#define EPACK_OFF  3414100    // u64[625,000] (8B-aligned)   -> 1,250,000 units
#define SLOT_OFF   4664100    // u32[625,000]
#define TMP_OFF    4664100    // ushort[6,400,000] overlays SLOT (dead after csr_fill); 16B-aligned

// ---------------- prep: zero cnt64 + convert W -> bf16 ----------------
__global__ void prep(const float* __restrict__ W, unsigned short* __restrict__ wb,
                     uint4* __restrict__ cntz) {
    int i = blockIdx.x * 256 + threadIdx.x;
    if (i < 100000 / 4) cntz[i] = make_uint4(0u, 0u, 0u, 0u);
    if (i < HIDDEN * HIDDEN) wb[i] = f2b(W[i]);
}

// ---------------- fused: GEMM tiles + edge histogram (8 edges/thread) ----------------
__global__ __launch_bounds__(256) void gemm_hist(const float* __restrict__ x,
                                                 const unsigned short* __restrict__ wb,
                                                 unsigned short* __restrict__ hb,
                                                 const int* __restrict__ dst,
                                                 const float* __restrict__ w,
                                                 u64* __restrict__ cnt64,
                                                 unsigned int* __restrict__ slot) {
    if (blockIdx.x >= NGEMM_BLK) {
        int base = (blockIdx.x - NGEMM_BLK) * 256 + threadIdx.x;   // 8-edge group id
        if (base * 8 >= N_EDGES) return;
        int4   dA = ((const int4*)dst)[base * 2];
        int4   dB = ((const int4*)dst)[base * 2 + 1];
        float4 wA = ((const float4*)w)[base * 2];
        float4 wB = ((const float4*)w)[base * 2 + 1];
        uint4 sA, sB;
        {
            unsigned int fx = (unsigned int)(wA.x * FIXSCALE + 0.5f);
            sA.x = (unsigned int)(atomicAdd(&cnt64[dA.x], (1ULL << 32) | (u64)fx) >> 32);
            fx = (unsigned int)(wA.y * FIXSCALE + 0.5f);
            sA.y = (unsigned int)(atomicAdd(&cnt64[dA.y], (1ULL << 32) | (u64)fx) >> 32);
            fx = (unsigned int)(wA.z * FIXSCALE + 0.5f);
            sA.z = (unsigned int)(atomicAdd(&cnt64[dA.z], (1ULL << 32) | (u64)fx) >> 32);
            fx = (unsigned int)(wA.w * FIXSCALE + 0.5f);
            sA.w = (unsigned int)(atomicAdd(&cnt64[dA.w], (1ULL << 32) | (u64)fx) >> 32);
            fx = (unsigned int)(wB.x * FIXSCALE + 0.5f);
            sB.x = (unsigned int)(atomicAdd(&cnt64[dB.x], (1ULL << 32) | (u64)fx) >> 32);
            fx = (unsigned int)(wB.y * FIXSCALE + 0.5f);
            sB.y = (unsigned int)(atomicAdd(&cnt64[dB.y], (1ULL << 32) | (u64)fx) >> 32);
            fx = (unsigned int)(wB.z * FIXSCALE + 0.5f);
            sB.z = (unsigned int)(atomicAdd(&cnt64[dB.z], (1ULL << 32) | (u64)fx) >> 32);
            fx = (unsigned int)(wB.w * FIXSCALE + 0.5f);
            sB.w = (unsigned int)(atomicAdd(&cnt64[dB.w], (1ULL << 32) | (u64)fx) >> 32);
        }
        ((uint4*)slot)[base * 2]     = sA;
        ((uint4*)slot)[base * 2 + 1] = sB;
        return;
    }
    // ---- GEMM part: h = x @ W.T ----
    const int wave = threadIdx.x >> 6;
    const int lane = threadIdx.x & 63;
    const int row0 = blockIdx.x * 64 + wave * 16;
    const int r  = lane & 15;
    const int ko = (lane >> 4) * 8;
    f32x4 acc[8];
#pragma unroll
    for (int t = 0; t < 8; ++t) { acc[t][0] = 0.f; acc[t][1] = 0.f; acc[t][2] = 0.f; acc[t][3] = 0.f; }
    int arow = row0 + r;
    if (arow >= N_NODES) arow = N_NODES - 1;
    const size_t abase = (size_t)arow * HIDDEN + ko;
#pragma unroll
    for (int kt = 0; kt < HIDDEN; kt += 32) {
        float4 a0 = *(const float4*)(x + abase + kt);
        float4 a1 = *(const float4*)(x + abase + kt + 4);
        bf16x8 a;
        a[0] = (__bf16)a0.x; a[1] = (__bf16)a0.y; a[2] = (__bf16)a0.z; a[3] = (__bf16)a0.w;
        a[4] = (__bf16)a1.x; a[5] = (__bf16)a1.y; a[6] = (__bf16)a1.z; a[7] = (__bf16)a1.w;
#pragma unroll
        for (int t = 0; t < 8; ++t) {
            bf16x8 b = *(const bf16x8*)(wb + (size_t)(t * 16 + r) * HIDDEN + kt + ko);
            acc[t] = __builtin_amdgcn_mfma_f32_16x16x32_bf16(a, b, acc[t], 0, 0, 0);
        }
    }
    const int orow = row0 + (lane >> 4) * 4;
#pragma unroll
    for (int t = 0; t < 8; ++t) {
#pragma unroll
        for (int j = 0; j < 4; ++j) {
            int rr = orow + j;
            if (rr < N_NODES) hb[(size_t)rr * HIDDEN + t * 16 + r] = f2b(acc[t][j]);
        }
    }
}

// ---------------- scan partials + dinv + graph bounds (fused) ----------------
__global__ void scan_partial(const u64* __restrict__ cnt64, int* __restrict__ bsum,
                             float* __restrict__ dinv,
                             const int* __restrict__ batch, int* __restrict__ gstart) {
    __shared__ int red[256];
    int i = blockIdx.x * 256 + threadIdx.x;
    int c = 0;
    if (i < N_NODES) {
        u64 v = cnt64[i];
        c = (int)(v >> 32);
        dinv[i] = rsqrtf(1.0f + (float)(unsigned int)v * (1.0f / FIXSCALE));
        int b0 = batch[i];
        int prev = (i == 0) ? -1 : batch[i - 1];
        for (int g = prev + 1; g <= b0; ++g) gstart[g] = i;
        if (i == N_NODES - 1) {
            for (int g = b0 + 1; g <= NUM_GRAPHS; ++g) gstart[g] = N_NODES;
        }
    }
    red[threadIdx.x] = c;
    __syncthreads();
    for (int off = 128; off > 0; off >>= 1) {
        if (threadIdx.x < off) red[threadIdx.x] += red[threadIdx.x + off];
        __syncthreads();
    }
    if (threadIdx.x == 0) bsum[blockIdx.x] = red[0];
}

// ---------------- scan_emit with inlined block-offset scan ----------------
__global__ void scan_emit(const u64* __restrict__ cnt64, const int* __restrict__ bsum,
                          int* __restrict__ rowstart) {
    __shared__ int sb[256];
    __shared__ int s[256];
    int t = threadIdx.x;
    sb[t] = (t < NB_SCAN) ? bsum[t] : 0;
    __syncthreads();
    for (int off = 1; off < 256; off <<= 1) {
        int v = (t >= off) ? sb[t - off] : 0;
        __syncthreads();
        sb[t] += v;
        __syncthreads();
    }
    int boff = (blockIdx.x == 0) ? 0 : sb[blockIdx.x - 1];
    int i = blockIdx.x * 256 + t;
    int v0 = (i < N_NODES) ? (int)(cnt64[i] >> 32) : 0;
    s[t] = v0;
    __syncthreads();
    for (int off = 1; off < 256; off <<= 1) {
        int v = (t >= off) ? s[t - off] : 0;
        __syncthreads();
        s[t] += v;
        __syncthreads();
    }
    if (i < N_NODES) rowstart[i] = boff + s[t] - v0;
    if (i == N_NODES) rowstart[N_NODES] = N_EDGES;
}

// ---------------- fill CSR: atomic-free, 4 edges/thread ----------------
__global__ void csr_fill(const int* __restrict__ src, const int* __restrict__ dst,
                         const float* __restrict__ w, const float* __restrict__ dinv,
                         const int* __restrict__ rowstart, const unsigned int* __restrict__ slot,
                         u64* __restrict__ epack) {
    int base = blockIdx.x * blockDim.x + threadIdx.x;
    if (base * 4 >= N_EDGES) return;
    int4   s4 = ((const int4*)src)[base];
    int4   d4 = ((const int4*)dst)[base];
    float4 w4 = ((const float4*)w)[base];
    uint4  r4 = ((const uint4*)slot)[base];
    float nm0 = dinv[s4.x] * w4.x * dinv[d4.x];
    float nm1 = dinv[s4.y] * w4.y * dinv[d4.y];
    float nm2 = dinv[s4.z] * w4.z * dinv[d4.z];
    float nm3 = dinv[s4.w] * w4.w * dinv[d4.w];
    epack[rowstart[d4.x] + (int)r4.x] = (u64)(unsigned int)s4.x | ((u64)__float_as_uint(nm0) << 32);
    epack[rowstart[d4.y] + (int)r4.y] = (u64)(unsigned int)s4.y | ((u64)__float_as_uint(nm1) << 32);
    epack[rowstart[d4.z] + (int)r4.z] = (u64)(unsigned int)s4.z | ((u64)__float_as_uint(nm2) << 32);
    epack[rowstart[d4.w] + (int)r4.w] = (u64)(unsigned int)s4.w | ((u64)__float_as_uint(nm3) << 32);
}

// ---------------- gather: 16 lanes/node, 4-edge unroll, writes bf16 tmp ----------------
__global__ __launch_bounds__(256) void gather_fused(const unsigned short* __restrict__ hb,
                                                    const int* __restrict__ rowstart,
                                                    const u64* __restrict__ epack,
                                                    const float* __restrict__ dinv,
                                                    const float* __restrict__ b,
                                                    unsigned short* __restrict__ tmp) {
    const int t = threadIdx.x;
    const int n = blockIdx.x * 16 + (t >> 4);
    if (n >= N_NODES) return;
    const int c8 = (t & 15) * 8;
    const int s0 = rowstart[n];
    const int e0 = rowstart[n + 1];
    const float di = dinv[n];
    const float sl = di * di;
    float acc[8];
    {
        u16x8 hv = *(const u16x8*)(hb + (size_t)n * HIDDEN + c8);
#pragma unroll
        for (int j = 0; j < 8; ++j) acc[j] = sl * b2f(hv[j]);
    }
    int p = s0;
    for (; p + 4 <= e0; p += 4) {
        u64 e1 = epack[p];
        u64 e2 = epack[p + 1];
        u64 e3 = epack[p + 2];
        u64 e4 = epack[p + 3];
        int   x1 = (int)(unsigned int)e1;
        int   x2 = (int)(unsigned int)e2;
        int   x3 = (int)(unsigned int)e3;
        int   x4 = (int)(unsigned int)e4;
        float n1 = __uint_as_float((unsigned int)(e1 >> 32));
        float n2 = __uint_as_float((unsigned int)(e2 >> 32));
        float n3 = __uint_as_float((unsigned int)(e3 >> 32));
        float n4 = __uint_as_float((unsigned int)(e4 >> 32));
        u16x8 v1 = *(const u16x8*)(hb + (size_t)x1 * HIDDEN + c8);
        u16x8 v2 = *(const u16x8*)(hb + (size_t)x2 * HIDDEN + c8);
        u16x8 v3 = *(const u16x8*)(hb + (size_t)x3 * HIDDEN + c8);
        u16x8 v4 = *(const u16x8*)(hb + (size_t)x4 * HIDDEN + c8);
#pragma unroll
        for (int j = 0; j < 8; ++j) acc[j] = fmaf(n1, b2f(v1[j]), acc[j]);
#pragma unroll
        for (int j = 0; j < 8; ++j) acc[j] = fmaf(n2, b2f(v2[j]), acc[j]);
#pragma unroll
        for (int j = 0; j < 8; ++j) acc[j] = fmaf(n3, b2f(v3[j]), acc[j]);
#pragma unroll
        for (int j = 0; j < 8; ++j) acc[j] = fmaf(n4, b2f(v4[j]), acc[j]);
    }
    for (; p < e0; ++p) {
        u64 e1 = epack[p];
        int   x1 = (int)(unsigned int)e1;
        float n1 = __uint_as_float((unsigned int)(e1 >> 32));
        u16x8 v1 = *(const u16x8*)(hb + (size_t)x1 * HIDDEN + c8);
#pragma unroll
        for (int j = 0; j < 8; ++j) acc[j] = fmaf(n1, b2f(v1[j]), acc[j]);
    }
    float4 b0 = *(const float4*)(b + c8);
    float4 b1 = *(const float4*)(b + c8 + 4);
    u16x8 o;
    o[0] = f2b(acc[0] + b0.x); o[1] = f2b(acc[1] + b0.y);
    o[2] = f2b(acc[2] + b0.z); o[3] = f2b(acc[3] + b0.w);
    o[4] = f2b(acc[4] + b1.x); o[5] = f2b(acc[5] + b1.y);
    o[6] = f2b(acc[6] + b1.z); o[7] = f2b(acc[7] + b1.w);
    *(u16x8*)(tmp + (size_t)n * HIDDEN + c8) = o;
}

// ---------------- fused per-graph stats + normalize + relu (u16x8 16B loads) ----------------
__global__ __launch_bounds__(256) void stats_apply(const unsigned short* __restrict__ tmp,
                                                   const int* __restrict__ gstart,
                                                   const float* __restrict__ ms,
                                                   const float* __restrict__ gw,
                                                   const float* __restrict__ gb,
                                                   float* __restrict__ out) {
    const int g = blockIdx.x >> 2;
    const int q = blockIdx.x & 3;
    const int l = threadIdx.x & 3;        // 4 col groups x 8 cols
    const int r = threadIdx.x >> 2;       // 0..63 rows in flight
    const int c0 = q * 32 + l * 8;
    const int s = gstart[g];
    const int e = gstart[g + 1];
    float sum[8], sq[8];
#pragma unroll
    for (int j = 0; j < 8; ++j) { sum[j] = 0.f; sq[j] = 0.f; }
    for (int n = s + r; n < e; n += 64) {
        u16x8 v = *(const u16x8*)(tmp + (size_t)n * HIDDEN + c0);
#pragma unroll
        for (int j = 0; j < 8; ++j) {
            float x = b2f(v[j]);
            sum[j] += x;
            sq[j] = fmaf(x, x, sq[j]);
        }
    }
    __shared__ float ssum[64][4][8];
    __shared__ float ssq[64][4][8];
    __shared__ float sA[32], sS[32];
#pragma unroll
    for (int j = 0; j < 8; ++j) { ssum[r][l][j] = sum[j]; ssq[r][l][j] = sq[j]; }
    __syncthreads();
    for (int off = 32; off > 0; off >>= 1) {
        if (r < off) {
#pragma unroll
            for (int j = 0; j < 8; ++j) {
                ssum[r][l][j] += ssum[r + off][l][j];
                ssq[r][l][j]  += ssq[r + off][l][j];
            }
        }
        __syncthreads();
    }
    if (r == 0) {
        float cnt = (float)max(e - s, 1);
#pragma unroll
        for (int j = 0; j < 8; ++j) {
            int c = c0 + j;
            float mean = ssum[0][l][j] / cnt;
            float m2   = ssq[0][l][j] / cnt;
            float msv  = ms[c];
            float var  = fmaxf(m2 - mean * mean * msv * (2.f - msv), 0.f);
            float a    = gw[c] * rsqrtf(var + EPS_GN);
            sA[l * 8 + j] = a;
            sS[l * 8 + j] = gb[c] - a * msv * mean;
        }
    }
    __syncthreads();
    float a[8], h[8];
#pragma unroll
    for (int j = 0; j < 8; ++j) { a[j] = sA[l * 8 + j]; h[j] = sS[l * 8 + j]; }
    for (int n = s + r; n < e; n += 64) {
        u16x8 v = *(const u16x8*)(tmp + (size_t)n * HIDDEN + c0);
        float4 o0, o1;
        o0.x = fmaxf(fmaf(a[0], b2f(v[0]), h[0]), 0.f);
        o0.y = fmaxf(fmaf(a[1], b2f(v[1]), h[1]), 0.f);
        o0.z = fmaxf(fmaf(a[2], b2f(v[2]), h[2]), 0.f);
        o0.w = fmaxf(fmaf(a[3], b2f(v[3]), h[3]), 0.f);
        o1.x = fmaxf(fmaf(a[4], b2f(v[4]), h[4]), 0.f);
        o1.y = fmaxf(fmaf(a[5], b2f(v[5]), h[5]), 0.f);
        o1.z = fmaxf(fmaf(a[6], b2f(v[6]), h[6]), 0.f);
        o1.w = fmaxf(fmaf(a[7], b2f(v[7]), h[7]), 0.f);
        *(float4*)(out + (size_t)n * HIDDEN + c0)     = o0;
        *(float4*)(out + (size_t)n * HIDDEN + c0 + 4) = o1;
    }
}

extern "C" void kernel_launch(void* const* d_in, const int* in_sizes, int n_in,
                              void* d_out, int out_size, void* d_ws, size_t ws_size,
                              hipStream_t stream) {
    const float* node  = (const float*)d_in[0];
    const int*   ei    = (const int*)d_in[1];
    const float* eattr = (const float*)d_in[2];
    const int*   batch = (const int*)d_in[3];
    const float* W     = (const float*)d_in[4];
    const float* b     = (const float*)d_in[5];
    const float* gnw   = (const float*)d_in[6];
    const float* gnb   = (const float*)d_in[7];
    const float* gnms  = (const float*)d_in[8];
    float* out = (float*)d_out;
    float* ws  = (float*)d_ws;

    const int* src = ei;
    const int* dst = ei + N_EDGES;

    unsigned short* hb = (unsigned short*)(ws + HB_OFF);
    u64*   cnt64   = (u64*)(ws + CNT64_OFF);
    float* dinv    = ws + DINV_OFF;
    unsigned short* wb = (unsigned short*)(ws + WB_OFF);
    int*   gstart  = (int*)(ws + GSTART_OFF);
    int*   rowstart= (int*)(ws + ROWS_OFF);
    int*   bsum    = (int*)(ws + BSUM_OFF);
    u64*   epack   = (u64*)(ws + EPACK_OFF);
    unsigned int* slot = (unsigned int*)(ws + SLOT_OFF);
    unsigned short* tmp = (unsigned short*)(ws + TMP_OFF);   // overlays slot (dead after csr_fill)

    prep<<<98, 256, 0, stream>>>(W, wb, (uint4*)cnt64);
    gemm_hist<<<NGEMM_BLK + NHIST_BLK, 256, 0, stream>>>(node, wb, hb, dst, eattr, cnt64, slot);
    scan_partial<<<NB_SCAN, 256, 0, stream>>>(cnt64, bsum, dinv, batch, gstart);
    scan_emit<<<NB_SCAN, 256, 0, stream>>>(cnt64, bsum, rowstart);
    csr_fill<<<(N_EDGES / 4 + 255) / 256, 256, 0, stream>>>(src, dst, eattr, dinv, rowstart, slot, epack);
    gather_fused<<<(N_NODES + 15) / 16, 256, 0, stream>>>(hb, rowstart, epack, dinv, b, tmp);
    stats_apply<<<NUM_GRAPHS * 4, 256, 0, stream>>>(tmp, gstart, gnms, gnw, gnb, out);

    (void)in_sizes; (void)n_in; (void)out_size; (void)ws_size;
}